// Round 1
// baseline (357.955 us; speedup 1.0000x reference)
//
#include <hip/hip_runtime.h>

typedef unsigned short u16;
typedef unsigned int u32;
typedef __bf16 bf16x8 __attribute__((ext_vector_type(8)));
typedef float f32x4 __attribute__((ext_vector_type(4)));
typedef u32 u32x4 __attribute__((ext_vector_type(4)));

#define NBATCH 4
#define NS 2048
#define ND 1024
#define NH 16
#define HDIM 64

#define MFMA(a, b, c) __builtin_amdgcn_mfma_f32_16x16x32_bf16(a, b, c, 0, 0, 0)

__device__ __forceinline__ u16 f2bf(float f) {
    u32 u = __builtin_bit_cast(u32, f);
    u += 0x7fffu + ((u >> 16) & 1u);
    return (u16)(u >> 16);
}

__device__ __forceinline__ bf16x8 ldfrag(const u16* p) {
    u32x4 v = *(const u32x4*)p;
    return __builtin_bit_cast(bf16x8, v);
}

__device__ __forceinline__ void gld16(u16* lds, const u16* g) {
    __builtin_amdgcn_global_load_lds((__attribute__((address_space(1))) u32*)g,
                                     (__attribute__((address_space(3))) u32*)lds, 16, 0, 0);
}

// ---------------- convert f32 -> bf16 (vectorized) ----------------
__global__ __launch_bounds__(256) void cvt_f32_bf16(const float* __restrict__ src,
                                                    u16* __restrict__ dst) {
    const size_t i = ((size_t)blockIdx.x * 256 + threadIdx.x) * 4;
    float4 v = *(const float4*)(src + i);
    uint2 o;
    o.x = (u32)f2bf(v.x) | ((u32)f2bf(v.y) << 16);
    o.y = (u32)f2bf(v.z) | ((u32)f2bf(v.w) << 16);
    *(uint2*)(dst + i) = o;
}

// ---------------- W [K][N] f32 -> WT [N][K] bf16 (tiled transpose) ----------------
__global__ __launch_bounds__(256) void wtrans(const float* __restrict__ W, u16* __restrict__ WT) {
    __shared__ u16 t[64][72];
    const int tid = threadIdx.x;
    const int k0 = blockIdx.x * 64, n0 = blockIdx.y * 64;
    {
        const int r = tid >> 2, cq = (tid & 3) * 16;
#pragma unroll
        for (int i = 0; i < 4; ++i) {
            float4 v = *(const float4*)(W + (size_t)(k0 + r) * ND + n0 + cq + i * 4);
            t[r][cq + i * 4 + 0] = f2bf(v.x);
            t[r][cq + i * 4 + 1] = f2bf(v.y);
            t[r][cq + i * 4 + 2] = f2bf(v.z);
            t[r][cq + i * 4 + 3] = f2bf(v.w);
        }
    }
    __syncthreads();
    {
        const int rr = tid >> 2, cq = (tid & 3) * 16;
        u32x4 o0, o1;
#pragma unroll
        for (int j = 0; j < 4; ++j) {
            o0[j] = (u32)t[cq + 2 * j][rr] | ((u32)t[cq + 2 * j + 1][rr] << 16);
            o1[j] = (u32)t[cq + 8 + 2 * j][rr] | ((u32)t[cq + 8 + 2 * j + 1][rr] << 16);
        }
        u16* out = WT + (size_t)(n0 + rr) * ND + k0 + cq;
        *(u32x4*)out = o0;
        *(u32x4*)(out + 8) = o1;
    }
}

// ---------------- V [bh][s][64] -> Vt [bh][64][s] ----------------
__global__ __launch_bounds__(256) void vtrans(const u16* __restrict__ V, u16* __restrict__ Vt) {
    __shared__ u16 t[64][72];
    const int tid = threadIdx.x;
    const int s0 = blockIdx.x * 64;
    const int bh = blockIdx.y;
    const u16* Vb = V + ((size_t)bh * NS + s0) * HDIM;
#pragma unroll
    for (int i = 0; i < 2; ++i) {
        int idx = i * 256 + tid;
        int r = idx >> 3, c = (idx & 7) * 8;
        u32x4 v = *(const u32x4*)(Vb + r * HDIM + c);
#pragma unroll
        for (int j = 0; j < 4; ++j) {
            t[r][c + 2 * j] = (u16)(v[j] & 0xffffu);
            t[r][c + 2 * j + 1] = (u16)(v[j] >> 16);
        }
    }
    __syncthreads();
    u16* Ob = Vt + (size_t)bh * HDIM * NS + s0;
#pragma unroll
    for (int i = 0; i < 2; ++i) {
        int idx = i * 256 + tid;
        int hd = idx >> 3, c = (idx & 7) * 8;
        u32x4 o;
#pragma unroll
        for (int j = 0; j < 4; ++j) {
            o[j] = (u32)t[c + 2 * j][hd] | ((u32)t[c + 2 * j + 1][hd] << 16);
        }
        *(u32x4*)(Ob + (size_t)hd * NS + c) = o;
    }
}

// ---------------- GEMM: C = A[M][1024] * Bt[N][1024]^T + bias, NT form ----------------
// MODE 1: bf16 out in QKV layout [(b*16+h)][s][hd]; MODE 2: f32 out [M][N]
template <int MODE>
__global__ __launch_bounds__(256) void gemm_bt(const u16* __restrict__ A, const u16* __restrict__ Bt,
                                               const float* __restrict__ bias, u16* __restrict__ obf,
                                               float* __restrict__ of32, float scale) {
    __shared__ u16 la[128 * 32];
    __shared__ u16 lb[128 * 32];
    const int tid = threadIdx.x;
    const int l = tid & 63, w = tid >> 6;
    const int lr = l & 15, lg = l >> 4;
    const int wr = w >> 1, wc = w & 1;
    const int m0 = blockIdx.y * 128, n0 = blockIdx.x * 128;

    // staging indices (swizzled source chunk so LDS[row][c] = A[row][c ^ ((row>>1)&3)<<4 bytes])
    const int idx0 = tid, idx1 = tid + 256;
    const int row0 = idx0 >> 2, row1 = idx1 >> 2;
    const int sc0 = ((idx0 & 3) ^ ((row0 >> 1) & 3)) * 8;
    const int sc1 = ((idx1 & 3) ^ ((row1 >> 1) & 3)) * 8;
    const u16* Ar0 = A + (size_t)(m0 + row0) * ND + sc0;
    const u16* Ar1 = A + (size_t)(m0 + row1) * ND + sc1;
    const u16* Br0 = Bt + (size_t)(n0 + row0) * ND + sc0;
    const u16* Br1 = Bt + (size_t)(n0 + row1) * ND + sc1;

    f32x4 acc[4][4] = {};

    for (int kt = 0; kt < 32; ++kt) {
        const int k0 = kt * 32;
        __syncthreads();
        gld16(&la[idx0 * 8], Ar0 + k0);
        gld16(&la[idx1 * 8], Ar1 + k0);
        gld16(&lb[idx0 * 8], Br0 + k0);
        gld16(&lb[idx1 * 8], Br1 + k0);
        __syncthreads();

        bf16x8 af[4], bv[4];
#pragma unroll
        for (int mb = 0; mb < 4; ++mb) {
            int row = wr * 64 + mb * 16 + lr;
            int off = row * 32 + (((lg * 16) ^ (((row >> 1) & 3) << 4)) >> 1);
            af[mb] = ldfrag(&la[off]);
        }
#pragma unroll
        for (int nb = 0; nb < 4; ++nb) {
            int row = wc * 64 + nb * 16 + lr;
            int off = row * 32 + (((lg * 16) ^ (((row >> 1) & 3) << 4)) >> 1);
            bv[nb] = ldfrag(&lb[off]);
        }
#pragma unroll
        for (int mb = 0; mb < 4; ++mb)
#pragma unroll
            for (int nb = 0; nb < 4; ++nb)
                acc[mb][nb] = MFMA(af[mb], bv[nb], acc[mb][nb]);
    }

    // epilogue: C/D layout col=lane&15, row=(lane>>4)*4+r
#pragma unroll
    for (int mb = 0; mb < 4; ++mb) {
#pragma unroll
        for (int nb = 0; nb < 4; ++nb) {
            const int col = n0 + wc * 64 + nb * 16 + lr;
            const float bia = bias[col];
#pragma unroll
            for (int r = 0; r < 4; ++r) {
                const int rowg = m0 + wr * 64 + mb * 16 + lg * 4 + r;
                float v = (acc[mb][nb][r] + bia) * scale;
                if (MODE == 2) {
                    of32[(size_t)rowg * ND + col] = v;
                } else {
                    // [b,h,s,hd] with b = rowg>>11, s = rowg&2047, h = col>>6, hd = col&63
                    size_t o = ((size_t)((rowg >> 11) * NH + (col >> 6)) * NS + (rowg & 2047)) * HDIM + (col & 63);
                    obf[o] = f2bf(v);
                }
            }
        }
    }
}

// ---------------- flash attention: Q[bh][s][64] (K pre-scaled by 1/8), Vt[bh][64][s] ----------------
__global__ __launch_bounds__(256) void attn(const u16* __restrict__ Q, const u16* __restrict__ K,
                                            const u16* __restrict__ Vt, u16* __restrict__ AO) {
    __shared__ u16 kl[64 * 64];       // [kv][hd], xor-swizzled rows
    __shared__ u16 vl[64 * 64];       // [hd][kv], xor-swizzled rows
    __shared__ u16 pl[4 * 32 * 64];   // per-wave P [32 q][64 kv], xor-swizzled
    const int tid = threadIdx.x;
    const int l = tid & 63, w = tid >> 6;
    const int lr = l & 15, lg = l >> 4;
    const int qb = blockIdx.x, bh = blockIdx.y;

    // Q fragments for this wave's 32 rows, kept in registers
    const u16* Qb = Q + ((size_t)bh * NS + qb * 128 + w * 32) * HDIM;
    bf16x8 qf[2][2];
#pragma unroll
    for (int mb = 0; mb < 2; ++mb)
#pragma unroll
        for (int kc = 0; kc < 2; ++kc)
            qf[mb][kc] = ldfrag(Qb + (mb * 16 + lr) * HDIM + kc * 32 + lg * 8);

    f32x4 oacc[2][4] = {};
    float mrow[2][4], lrow[2][4];
#pragma unroll
    for (int mb = 0; mb < 2; ++mb)
#pragma unroll
        for (int r = 0; r < 4; ++r) { mrow[mb][r] = -1e30f; lrow[mb][r] = 0.f; }

    const u16* Kb = K + (size_t)bh * NS * HDIM;
    const u16* Vb = Vt + (size_t)bh * HDIM * NS;
    u16* pw = &pl[w * 2048];

    const int sidx0 = tid, sidx1 = tid + 256;
    const int srow0 = sidx0 >> 3, srow1 = sidx1 >> 3;
    const int ssc0 = ((sidx0 & 7) ^ (srow0 & 7)) * 8;
    const int ssc1 = ((sidx1 & 7) ^ (srow1 & 7)) * 8;

    for (int kt = 0; kt < NS / 64; ++kt) {
        __syncthreads();
        gld16(&kl[sidx0 * 8], Kb + (size_t)(kt * 64 + srow0) * HDIM + ssc0);
        gld16(&kl[sidx1 * 8], Kb + (size_t)(kt * 64 + srow1) * HDIM + ssc1);
        gld16(&vl[sidx0 * 8], Vb + (size_t)srow0 * NS + kt * 64 + ssc0);
        gld16(&vl[sidx1 * 8], Vb + (size_t)srow1 * NS + kt * 64 + ssc1);
        __syncthreads();

        // S = Q * K^T (pre-scaled)
        f32x4 sacc[2][4] = {};
#pragma unroll
        for (int kc = 0; kc < 2; ++kc) {
            bf16x8 kf[4];
#pragma unroll
            for (int nb = 0; nb < 4; ++nb) {
                int row = nb * 16 + lr;
                int off = row * 64 + (((kc * 64 + lg * 16) ^ ((row & 7) << 4)) >> 1);
                kf[nb] = ldfrag(&kl[off]);
            }
#pragma unroll
            for (int mb = 0; mb < 2; ++mb)
#pragma unroll
                for (int nb = 0; nb < 4; ++nb)
                    sacc[mb][nb] = MFMA(qf[mb][kc], kf[nb], sacc[mb][nb]);
        }

        // online softmax (rows spread over 16 lanes: masks 1..8)
#pragma unroll
        for (int mb = 0; mb < 2; ++mb) {
#pragma unroll
            for (int r = 0; r < 4; ++r) {
                float tm = fmaxf(fmaxf(sacc[mb][0][r], sacc[mb][1][r]),
                                 fmaxf(sacc[mb][2][r], sacc[mb][3][r]));
#pragma unroll
                for (int sh = 1; sh <= 8; sh <<= 1) tm = fmaxf(tm, __shfl_xor(tm, sh));
                const float mo = mrow[mb][r];
                const float mn = fmaxf(mo, tm);
                const float corr = __expf(mo - mn);
                float rs = 0.f;
#pragma unroll
                for (int nb = 0; nb < 4; ++nb) {
                    float p = __expf(sacc[mb][nb][r] - mn);
                    sacc[mb][nb][r] = p;
                    rs += p;
                }
#pragma unroll
                for (int sh = 1; sh <= 8; sh <<= 1) rs += __shfl_xor(rs, sh);
                lrow[mb][r] = lrow[mb][r] * corr + rs;
                mrow[mb][r] = mn;
#pragma unroll
                for (int nb = 0; nb < 4; ++nb) oacc[mb][nb][r] *= corr;
            }
        }

        // P -> per-wave LDS (bf16, swizzled)
#pragma unroll
        for (int mb = 0; mb < 2; ++mb)
#pragma unroll
            for (int r = 0; r < 4; ++r) {
                int prow = mb * 16 + lg * 4 + r;
#pragma unroll
                for (int nb = 0; nb < 4; ++nb) {
                    int pcol = nb * 16 + lr;
                    int off = prow * 64 + (((pcol * 2) ^ ((prow & 7) << 4)) >> 1);
                    pw[off] = f2bf(sacc[mb][nb][r]);
                }
            }

        // O += P * V
#pragma unroll
        for (int kc = 0; kc < 2; ++kc) {
            bf16x8 pf[2], vf[4];
#pragma unroll
            for (int mb = 0; mb < 2; ++mb) {
                int row = mb * 16 + lr;
                int off = row * 64 + (((kc * 64 + lg * 16) ^ ((row & 7) << 4)) >> 1);
                pf[mb] = ldfrag(&pw[off]);
            }
#pragma unroll
            for (int nb = 0; nb < 4; ++nb) {
                int row = nb * 16 + lr;
                int off = row * 64 + (((kc * 64 + lg * 16) ^ ((row & 7) << 4)) >> 1);
                vf[nb] = ldfrag(&vl[off]);
            }
#pragma unroll
            for (int mb = 0; mb < 2; ++mb)
#pragma unroll
                for (int nb = 0; nb < 4; ++nb)
                    oacc[mb][nb] = MFMA(pf[mb], vf[nb], oacc[mb][nb]);
        }
    }

    // epilogue -> AO [b][s][h*64+hd] bf16
    const int b = bh >> 4, h = bh & 15;
#pragma unroll
    for (int mb = 0; mb < 2; ++mb)
#pragma unroll
        for (int r = 0; r < 4; ++r) {
            const float inv = 1.f / lrow[mb][r];
            const int srow = qb * 128 + w * 32 + mb * 16 + lg * 4 + r;
#pragma unroll
            for (int nb = 0; nb < 4; ++nb) {
                const int col = h * 64 + nb * 16 + lr;
                AO[((size_t)b * NS + srow) * ND + col] = f2bf(oacc[mb][nb][r] * inv);
            }
        }
}

extern "C" void kernel_launch(void* const* d_in, const int* in_sizes, int n_in,
                              void* d_out, int out_size, void* d_ws, size_t ws_size,
                              hipStream_t stream) {
    const float* x = (const float*)d_in[0];
    const float* Wq = (const float*)d_in[1];
    const float* bq = (const float*)d_in[2];
    const float* Wk = (const float*)d_in[3];
    const float* bk = (const float*)d_in[4];
    const float* Wv = (const float*)d_in[5];
    const float* bv = (const float*)d_in[6];
    const float* Wo = (const float*)d_in[7];
    const float* bo = (const float*)d_in[8];
    float* out = (float*)d_out;

    u16* ws = (u16*)d_ws;
    u16* xb = ws;                    // 8192x1024 bf16 (reused as AO after QKV)
    u16* wqT = ws + 8388608;
    u16* wkT = wqT + 1048576;
    u16* wvT = wkT + 1048576;
    u16* woT = wvT + 1048576;
    u16* Qp = woT + 1048576;
    u16* Kp = Qp + 8388608;
    u16* Vp = Kp + 8388608;
    u16* Vtp = Vp + 8388608;
    u16* AO = xb;

    cvt_f32_bf16<<<8192, 256, 0, stream>>>(x, xb);
    dim3 tg(16, 16);
    wtrans<<<tg, 256, 0, stream>>>(Wq, wqT);
    wtrans<<<tg, 256, 0, stream>>>(Wk, wkT);
    wtrans<<<tg, 256, 0, stream>>>(Wv, wvT);
    wtrans<<<tg, 256, 0, stream>>>(Wo, woT);
    dim3 gg(8, 64);
    gemm_bt<1><<<gg, 256, 0, stream>>>(xb, wqT, bq, Qp, nullptr, 1.0f);
    gemm_bt<1><<<gg, 256, 0, stream>>>(xb, wkT, bk, Kp, nullptr, 0.125f);  // fold 1/sqrt(64) into K
    gemm_bt<1><<<gg, 256, 0, stream>>>(xb, wvT, bv, Vp, nullptr, 1.0f);
    vtrans<<<dim3(32, 64), 256, 0, stream>>>(Vp, Vtp);
    attn<<<dim3(16, 64), 256, 0, stream>>>(Qp, Kp, Vtp, AO);
    gemm_bt<2><<<gg, 256, 0, stream>>>(AO, woT, bo, nullptr, out, 1.0f);
}

// Round 2
// 248.472 us; speedup vs baseline: 1.4406x; 1.4406x over previous
//
#include <hip/hip_runtime.h>

typedef unsigned short u16;
typedef unsigned int u32;
typedef __bf16 bf16x8 __attribute__((ext_vector_type(8)));
typedef float f32x4 __attribute__((ext_vector_type(4)));
typedef float f32x16 __attribute__((ext_vector_type(16)));
typedef u32 u32x4 __attribute__((ext_vector_type(4)));
typedef u32 u32x2 __attribute__((ext_vector_type(2)));

#define NBATCH 4
#define NS 2048
#define ND 1024
#define NH 16
#define HDIM 64

#define MFMA(a, b, c) __builtin_amdgcn_mfma_f32_16x16x32_bf16(a, b, c, 0, 0, 0)
#define MFMA32(a, b, c) __builtin_amdgcn_mfma_f32_32x32x16_bf16(a, b, c, 0, 0, 0)

__device__ __forceinline__ u16 f2bf(float f) {
    u32 u = __builtin_bit_cast(u32, f);
    u += 0x7fffu + ((u >> 16) & 1u);
    return (u16)(u >> 16);
}

__device__ __forceinline__ u32 cvtpk(float a, float b) {
    u32 r;
    asm("v_cvt_pk_bf16_f32 %0, %1, %2" : "=v"(r) : "v"(a), "v"(b));
    return r;
}

__device__ __forceinline__ bf16x8 ldfrag(const u16* p) {
    u32x4 v = *(const u32x4*)p;
    return __builtin_bit_cast(bf16x8, v);
}

__device__ __forceinline__ void gld16(u16* lds, const u16* g) {
    __builtin_amdgcn_global_load_lds((__attribute__((address_space(1))) u32*)g,
                                     (__attribute__((address_space(3))) u32*)lds, 16, 0, 0);
}

// ---------------- convert f32 -> bf16 (vectorized) ----------------
__global__ __launch_bounds__(256) void cvt_f32_bf16(const float* __restrict__ src,
                                                    u16* __restrict__ dst) {
    const size_t i = ((size_t)blockIdx.x * 256 + threadIdx.x) * 4;
    float4 v = *(const float4*)(src + i);
    uint2 o;
    o.x = (u32)f2bf(v.x) | ((u32)f2bf(v.y) << 16);
    o.y = (u32)f2bf(v.z) | ((u32)f2bf(v.w) << 16);
    *(uint2*)(dst + i) = o;
}

// ---------------- W [K][N] f32 -> WT [N][K] bf16 (tiled transpose) ----------------
__global__ __launch_bounds__(256) void wtrans(const float* __restrict__ W, u16* __restrict__ WT) {
    __shared__ u16 t[64][72];
    const int tid = threadIdx.x;
    const int k0 = blockIdx.x * 64, n0 = blockIdx.y * 64;
    {
        const int r = tid >> 2, cq = (tid & 3) * 16;
#pragma unroll
        for (int i = 0; i < 4; ++i) {
            float4 v = *(const float4*)(W + (size_t)(k0 + r) * ND + n0 + cq + i * 4);
            t[r][cq + i * 4 + 0] = f2bf(v.x);
            t[r][cq + i * 4 + 1] = f2bf(v.y);
            t[r][cq + i * 4 + 2] = f2bf(v.z);
            t[r][cq + i * 4 + 3] = f2bf(v.w);
        }
    }
    __syncthreads();
    {
        const int rr = tid >> 2, cq = (tid & 3) * 16;
        u32x4 o0, o1;
#pragma unroll
        for (int j = 0; j < 4; ++j) {
            o0[j] = (u32)t[cq + 2 * j][rr] | ((u32)t[cq + 2 * j + 1][rr] << 16);
            o1[j] = (u32)t[cq + 8 + 2 * j][rr] | ((u32)t[cq + 8 + 2 * j + 1][rr] << 16);
        }
        u16* out = WT + (size_t)(n0 + rr) * ND + k0 + cq;
        *(u32x4*)out = o0;
        *(u32x4*)(out + 8) = o1;
    }
}

// ---------------- V [bh][s][64] -> Vt [bh][64][s] ----------------
__global__ __launch_bounds__(256) void vtrans(const u16* __restrict__ V, u16* __restrict__ Vt) {
    __shared__ u16 t[64][72];
    const int tid = threadIdx.x;
    const int s0 = blockIdx.x * 64;
    const int bh = blockIdx.y;
    const u16* Vb = V + ((size_t)bh * NS + s0) * HDIM;
#pragma unroll
    for (int i = 0; i < 2; ++i) {
        int idx = i * 256 + tid;
        int r = idx >> 3, c = (idx & 7) * 8;
        u32x4 v = *(const u32x4*)(Vb + r * HDIM + c);
#pragma unroll
        for (int j = 0; j < 4; ++j) {
            t[r][c + 2 * j] = (u16)(v[j] & 0xffffu);
            t[r][c + 2 * j + 1] = (u16)(v[j] >> 16);
        }
    }
    __syncthreads();
    u16* Ob = Vt + (size_t)bh * HDIM * NS + s0;
#pragma unroll
    for (int i = 0; i < 2; ++i) {
        int idx = i * 256 + tid;
        int hd = idx >> 3, c = (idx & 7) * 8;
        u32x4 o;
#pragma unroll
        for (int j = 0; j < 4; ++j) {
            o[j] = (u32)t[c + 2 * j][hd] | ((u32)t[c + 2 * j + 1][hd] << 16);
        }
        *(u32x4*)(Ob + (size_t)hd * NS + c) = o;
    }
}

// ---------------- GEMM: C = A[M][1024] * Bt[N][1024]^T + bias, NT form ----------------
// MODE 1: bf16 out in QKV layout [(b*16+h)][s][hd]; MODE 2: f32 out [M][N]
template <int MODE>
__global__ __launch_bounds__(256) void gemm_bt(const u16* __restrict__ A, const u16* __restrict__ Bt,
                                               const float* __restrict__ bias, u16* __restrict__ obf,
                                               float* __restrict__ of32, float scale) {
    __shared__ u16 la[128 * 32];
    __shared__ u16 lb[128 * 32];
    const int tid = threadIdx.x;
    const int l = tid & 63, w = tid >> 6;
    const int lr = l & 15, lg = l >> 4;
    const int wr = w >> 1, wc = w & 1;
    const int m0 = blockIdx.y * 128, n0 = blockIdx.x * 128;

    const int idx0 = tid, idx1 = tid + 256;
    const int row0 = idx0 >> 2, row1 = idx1 >> 2;
    const int sc0 = ((idx0 & 3) ^ ((row0 >> 1) & 3)) * 8;
    const int sc1 = ((idx1 & 3) ^ ((row1 >> 1) & 3)) * 8;
    const u16* Ar0 = A + (size_t)(m0 + row0) * ND + sc0;
    const u16* Ar1 = A + (size_t)(m0 + row1) * ND + sc1;
    const u16* Br0 = Bt + (size_t)(n0 + row0) * ND + sc0;
    const u16* Br1 = Bt + (size_t)(n0 + row1) * ND + sc1;

    f32x4 acc[4][4] = {};

    for (int kt = 0; kt < 32; ++kt) {
        const int k0 = kt * 32;
        __syncthreads();
        gld16(&la[idx0 * 8], Ar0 + k0);
        gld16(&la[idx1 * 8], Ar1 + k0);
        gld16(&lb[idx0 * 8], Br0 + k0);
        gld16(&lb[idx1 * 8], Br1 + k0);
        __syncthreads();

        bf16x8 af[4], bv[4];
#pragma unroll
        for (int mb = 0; mb < 4; ++mb) {
            int row = wr * 64 + mb * 16 + lr;
            int off = row * 32 + (((lg * 16) ^ (((row >> 1) & 3) << 4)) >> 1);
            af[mb] = ldfrag(&la[off]);
        }
#pragma unroll
        for (int nb = 0; nb < 4; ++nb) {
            int row = wc * 64 + nb * 16 + lr;
            int off = row * 32 + (((lg * 16) ^ (((row >> 1) & 3) << 4)) >> 1);
            bv[nb] = ldfrag(&lb[off]);
        }
#pragma unroll
        for (int mb = 0; mb < 4; ++mb)
#pragma unroll
            for (int nb = 0; nb < 4; ++nb)
                acc[mb][nb] = MFMA(af[mb], bv[nb], acc[mb][nb]);
    }

#pragma unroll
    for (int mb = 0; mb < 4; ++mb) {
#pragma unroll
        for (int nb = 0; nb < 4; ++nb) {
            const int col = n0 + wc * 64 + nb * 16 + lr;
            const float bia = bias[col];
#pragma unroll
            for (int r = 0; r < 4; ++r) {
                const int rowg = m0 + wr * 64 + mb * 16 + lg * 4 + r;
                float v = (acc[mb][nb][r] + bia) * scale;
                if (MODE == 2) {
                    of32[(size_t)rowg * ND + col] = v;
                } else {
                    size_t o = ((size_t)((rowg >> 11) * NH + (col >> 6)) * NS + (rowg & 2047)) * HDIM + (col & 63);
                    obf[o] = f2bf(v);
                }
            }
        }
    }
}

// ---------------- flash attention, 32x32 swapped-operand structure ----------------
// Q[bh][s][64], K[bh][s][64] (pre-scaled by 0.125*log2e), Vt[bh][64][s]
// Per wave: 32 q rows. S^T = mfma32(Kfrag, Qfrag): lane holds P[kv 32 of 64][q=lane&31].
// In-register softmax (1 shfl per reduce); P packed to PV B-frags via cvt_pk + permlane32_swap.
// PV computes O^T = Vt * P^T (col = q = lane&31 -> per-lane rescale). Epilogue via LDS transpose.
__global__ __launch_bounds__(256) void attn(const u16* __restrict__ Q, const u16* __restrict__ K,
                                            const u16* __restrict__ Vt, u16* __restrict__ AO) {
    __shared__ u16 sm[8192];  // kl[64][64] + vl[64][64], both xor-swizzled; reused for epilogue
    u16* kl = sm;
    u16* vl = sm + 4096;
    const int tid = threadIdx.x;
    const int l = tid & 63, w = tid >> 6;
    const int lq = l & 31, hi = l >> 5;
    const int qb = blockIdx.x, bh = blockIdx.y;
    const int qbase = qb * 128 + w * 32;

    // Q fragments (B-operand: col=q=lane&31, k=hd=kh*16+hi*8+j), kept in registers
    const u16* Qrow = Q + ((size_t)bh * NS + qbase + lq) * HDIM;
    bf16x8 qf[4];
#pragma unroll
    for (int kh = 0; kh < 4; ++kh) qf[kh] = ldfrag(Qrow + kh * 16 + hi * 8);

    f32x16 oacc[2] = {};  // O^T: hdb tiles; col=q=lane&31, row=hd pattern
    float mrun = -3e38f, lsum = 0.f;

    const u16* Kb = K + (size_t)bh * NS * HDIM;
    const u16* Vb = Vt + (size_t)bh * HDIM * NS;

    const int sidx0 = tid, sidx1 = tid + 256;
    const int srow0 = sidx0 >> 3, srow1 = sidx1 >> 3;
    const int ssc0 = ((sidx0 & 7) ^ (srow0 & 7)) * 8;
    const int ssc1 = ((sidx1 & 7) ^ (srow1 & 7)) * 8;

    for (int kt = 0; kt < NS / 64; ++kt) {
        __syncthreads();
        gld16(&kl[sidx0 * 8], Kb + (size_t)(kt * 64 + srow0) * HDIM + ssc0);
        gld16(&kl[sidx1 * 8], Kb + (size_t)(kt * 64 + srow1) * HDIM + ssc1);
        gld16(&vl[sidx0 * 8], Vb + (size_t)srow0 * NS + kt * 64 + ssc0);
        gld16(&vl[sidx1 * 8], Vb + (size_t)srow1 * NS + kt * 64 + ssc1);
        __syncthreads();

        // S^T = K * Q^T : sacc[kvb] holds kv = kvb*32 + (reg&3)+8*(reg>>2)+4*hi, q = lane&31
        f32x16 sacc[2] = {};
#pragma unroll
        for (int kvb = 0; kvb < 2; ++kvb) {
            const int krow = kvb * 32 + lq;
            const int kbase = krow * 64;
            const int ksw = (krow & 7) << 4;
#pragma unroll
            for (int kh = 0; kh < 4; ++kh) {
                bf16x8 kf = ldfrag(&kl[kbase + (((kh * 32 + hi * 16) ^ ksw) >> 1)]);
                sacc[kvb] = MFMA32(kf, qf[kh], sacc[kvb]);
            }
        }

        // in-register online softmax over this lane's 32 kv values (q = lane&31)
        float pmax = -3e38f;
#pragma unroll
        for (int kvb = 0; kvb < 2; ++kvb)
#pragma unroll
            for (int i = 0; i < 16; ++i) pmax = fmaxf(pmax, sacc[kvb][i]);
        pmax = fmaxf(pmax, __shfl_xor(pmax, 32));

        const bool norescale = __all(pmax <= mrun + 8.0f);
        const float mn = norescale ? mrun : fmaxf(mrun, pmax);
        float rs = 0.f;
#pragma unroll
        for (int kvb = 0; kvb < 2; ++kvb)
#pragma unroll
            for (int i = 0; i < 16; ++i) {
                float p = __builtin_amdgcn_exp2f(sacc[kvb][i] - mn);
                sacc[kvb][i] = p;
                rs += p;
            }
        rs += __shfl_xor(rs, 32);
        if (norescale) {
            lsum += rs;
        } else {
            const float corr = __builtin_amdgcn_exp2f(mrun - mn);
            lsum = lsum * corr + rs;
            mrun = mn;
#pragma unroll
            for (int hdb = 0; hdb < 2; ++hdb)
#pragma unroll
                for (int i = 0; i < 16; ++i) oacc[hdb][i] *= corr;
        }

        // pack P -> PV B-fragments: pf[ks], kv = ks*16 + hi*8 + j for this lane's q
        bf16x8 pf[4];
#pragma unroll
        for (int ks = 0; ks < 4; ++ks) {
            const int i0 = 2 * ks, i1 = 2 * ks + 1;
            const int q20 = i0 & 3, kvb0 = i0 >> 2;
            const int q21 = i1 & 3, kvb1 = i1 >> 2;
            u32 W00 = cvtpk(sacc[kvb0][4 * q20 + 0], sacc[kvb0][4 * q20 + 1]);
            u32 W01 = cvtpk(sacc[kvb0][4 * q20 + 2], sacc[kvb0][4 * q20 + 3]);
            u32 W10 = cvtpk(sacc[kvb1][4 * q21 + 0], sacc[kvb1][4 * q21 + 1]);
            u32 W11 = cvtpk(sacc[kvb1][4 * q21 + 2], sacc[kvb1][4 * q21 + 3]);
            u32x2 s0 = __builtin_amdgcn_permlane32_swap(W00, W10, false, false);
            u32x2 s1 = __builtin_amdgcn_permlane32_swap(W01, W11, false, false);
            u32x4 words;
            words[0] = s0[0];
            words[1] = s1[0];
            words[2] = s0[1];
            words[3] = s1[1];
            pf[ks] = __builtin_bit_cast(bf16x8, words);
        }

        // O^T += Vt-frag * P^T
#pragma unroll
        for (int hdb = 0; hdb < 2; ++hdb) {
            const int vrow = hdb * 32 + lq;
            const int vbase = vrow * 64;
            const int vsw = (vrow & 7) << 4;
#pragma unroll
            for (int ks = 0; ks < 4; ++ks) {
                bf16x8 vf = ldfrag(&vl[vbase + (((ks * 32 + hi * 16) ^ vsw) >> 1)]);
                oacc[hdb] = MFMA32(vf, pf[ks], oacc[hdb]);
            }
        }
    }

    // epilogue: O^T -> per-wave LDS transpose -> coalesced AO rows
    __syncthreads();  // staging LDS no longer needed by any wave
    u16* ot = sm + w * 2048;  // [32 q][64 hd] u16, xor-swizzled rows
    const float inv = 1.f / lsum;
#pragma unroll
    for (int hdb = 0; hdb < 2; ++hdb)
#pragma unroll
        for (int q2 = 0; q2 < 4; ++q2)
#pragma unroll
            for (int rp = 0; rp < 2; ++rp) {
                u32 word = cvtpk(oacc[hdb][4 * q2 + 2 * rp] * inv, oacc[hdb][4 * q2 + 2 * rp + 1] * inv);
                const int hd0 = hdb * 32 + 8 * q2 + 4 * hi + 2 * rp;
                const int byteoff = lq * 128 + ((2 * hd0) ^ ((lq & 7) << 4));
                *(u32*)((char*)ot + byteoff) = word;
            }
    const int b = bh >> 4, h = bh & 15;
#pragma unroll
    for (int p = 0; p < 4; ++p) {
        const int idx = p * 64 + l;
        const int row = idx >> 3;
        const int cb = ((idx & 7) * 16) ^ ((row & 7) << 4);
        u32x4 val = *(u32x4*)((char*)ot + row * 128 + cb);
        const int srow = qbase - w * 32 + w * 32 + row;  // qb*128 + w*32 + row
        *(u32x4*)(AO + ((size_t)b * NS + qbase + row) * ND + h * 64 + (idx & 7) * 8) = val;
        (void)srow;
    }
}

extern "C" void kernel_launch(void* const* d_in, const int* in_sizes, int n_in,
                              void* d_out, int out_size, void* d_ws, size_t ws_size,
                              hipStream_t stream) {
    const float* x = (const float*)d_in[0];
    const float* Wq = (const float*)d_in[1];
    const float* bq = (const float*)d_in[2];
    const float* Wk = (const float*)d_in[3];
    const float* bk = (const float*)d_in[4];
    const float* Wv = (const float*)d_in[5];
    const float* bv = (const float*)d_in[6];
    const float* Wo = (const float*)d_in[7];
    const float* bo = (const float*)d_in[8];
    float* out = (float*)d_out;

    u16* ws = (u16*)d_ws;
    u16* xb = ws;
    u16* wqT = ws + 8388608;
    u16* wkT = wqT + 1048576;
    u16* wvT = wkT + 1048576;
    u16* woT = wvT + 1048576;
    u16* Qp = woT + 1048576;
    u16* Kp = Qp + 8388608;
    u16* Vp = Kp + 8388608;
    u16* Vtp = Vp + 8388608;
    u16* AO = xb;

    cvt_f32_bf16<<<8192, 256, 0, stream>>>(x, xb);
    dim3 tg(16, 16);
    wtrans<<<tg, 256, 0, stream>>>(Wq, wqT);
    wtrans<<<tg, 256, 0, stream>>>(Wk, wkT);
    wtrans<<<tg, 256, 0, stream>>>(Wv, wvT);
    wtrans<<<tg, 256, 0, stream>>>(Wo, woT);
    dim3 gg(8, 64);
    gemm_bt<1><<<gg, 256, 0, stream>>>(xb, wqT, bq, Qp, nullptr, 1.0f);
    // fold 1/sqrt(64) AND log2(e) into K so softmax exp is a raw exp2
    gemm_bt<1><<<gg, 256, 0, stream>>>(xb, wkT, bk, Kp, nullptr, 0.125f * 1.44269504f);
    gemm_bt<1><<<gg, 256, 0, stream>>>(xb, wvT, bv, Vp, nullptr, 1.0f);
    vtrans<<<dim3(32, 64), 256, 0, stream>>>(Vp, Vtp);
    attn<<<dim3(16, 64), 256, 0, stream>>>(Qp, Kp, Vtp, AO);
    gemm_bt<2><<<gg, 256, 0, stream>>>(AO, woT, bo, nullptr, out, 1.0f);
}